// Round 6
// baseline (1201.242 us; speedup 1.0000x reference)
//
#include <hip/hip_runtime.h>

// Problem constants
#define BB    512
#define TT    300
#define DD    128
#define HH    256
#define GG    1024      // 4*H
#define DNS   256
#define NC    14
#define KDIM  76800     // T*H

typedef _Float16 f16;
typedef _Float16 f16x8 __attribute__((ext_vector_type(8)));
typedef float    f32x4 __attribute__((ext_vector_type(4)));

__device__ __forceinline__ float sigf(float x){ return 1.0f / (1.0f + __expf(-x)); }
__device__ __forceinline__ float tanhfast(float x){ return 2.0f / (1.0f + __expf(-2.0f*x)) - 1.0f; }

// ---------------- K1: embedding gather, fp32 -> fp16 x[B][T][D] ----------------
__global__ void k_gather(const int* __restrict__ idx, const float* __restrict__ emb,
                         f16* __restrict__ xbuf)
{
    int gid = blockIdx.x * 256 + threadIdx.x;       // one 4-dim chunk
    if (gid >= BB*TT*DD/4) return;
    int bt = gid >> 5;                              // 32 chunks per 128-dim row
    int c4 = gid & 31;
    int v  = idx[bt];
    const float4 e = *(const float4*)(emb + (size_t)v*DD + c4*4);
    union { f16 h[4]; uint2 u; } o;
    o.h[0]=(f16)e.x; o.h[1]=(f16)e.y; o.h[2]=(f16)e.z; o.h[3]=(f16)e.w;
    *(uint2*)(xbuf + (size_t)bt*DD + c4*4) = o.u;
}

// ---------------- K1b: W3 fp32 -> fp16 ----------------
__global__ void k_w3cvt(const float* __restrict__ W3, f16* __restrict__ W3h)
{
    int gid = blockIdx.x * 256 + threadIdx.x;       // one float4
    if (gid >= DNS*KDIM/4) return;
    const float4 e = *(const float4*)(W3 + (size_t)gid*4);
    union { f16 h[4]; uint2 u; } o;
    o.h[0]=(f16)e.x; o.h[1]=(f16)e.y; o.h[2]=(f16)e.z; o.h[3]=(f16)e.w;
    *(uint2*)(W3h + (size_t)gid*4) = o.u;
}

// ---------------- K2: persistent LSTM recurrence ----------------
// Grid: 256 blocks = 16 h-slices (hsI) x 16 batch-slices (bsI); 512 threads (8 waves).
// W slice resident in registers.
// Round-6 exchange: TAG-IN-WORD dataflow. Each h element is one 4B word
// (t<<16)|f16bits in a depth-2 ping-pong hpp[t&1][b][dim]. Producer threads
// store their word right after elementwise (no vmcnt drain, no flag, no
// packing). Consumers poll exactly the 16 words they need until tag==t-1;
// validity travels WITH the data in one atomic word. Serial chain per step
// collapses to ~1.5 MALL RTTs. Depth-2 ping-pong is race-free: a producer
// reaches step t+2 (same slot) only after consuming h(t+1), which peers
// publish only after reading h(t). Poison 0xAA -> tag 0xAAAA != t: no init.
__global__ __launch_bounds__(512) void k_lstm(
    const f16* __restrict__ xbuf, f16* __restrict__ hs,
    const float* __restrict__ Wih, const float* __restrict__ Whh,
    const float* __restrict__ bih, const float* __restrict__ bhh,
    unsigned int* hpp)
{
    __shared__ f16   Ast[32*392];    // 32 rows x (256 h | 128 x | 8 pad) halves
    __shared__ float gbuf[32*68];    // gates [row][q] (q=4*d+ty), pad 68
    __shared__ float biasS[64];

    const int tid  = threadIdx.x;
    const int bsI  = blockIdx.x & 15, hsI = blockIdx.x >> 4;
    const int r0   = bsI*32, j0 = hsI*16;
    const int wv   = tid >> 6, lane = tid & 63;
    const int q16  = lane & 15, quad = lane >> 4;
    const int mt   = wv >> 2, nt = wv & 3;          // wave -> (m-subtile, n-subtile)

    // ---- load resident W fragments: lane holds W[q = nt*16+q16][k-chunks] ----
    f16x8 bf[12];
    {
        const int ql   = nt*16 + q16;
        const int drow = ql >> 2, ty = ql & 3;      // q = 4*d + ty
        const int Grow = ty*HH + j0 + drow;         // global gate row
        const float* wh = Whh + (size_t)Grow*HH;
        #pragma unroll
        for (int kk = 0; kk < 8; ++kk) {
            const float* p = wh + kk*32 + quad*8;
            float4 f0 = *(const float4*)p, f1 = *(const float4*)(p+4);
            f16x8 b;
            b[0]=(f16)f0.x; b[1]=(f16)f0.y; b[2]=(f16)f0.z; b[3]=(f16)f0.w;
            b[4]=(f16)f1.x; b[5]=(f16)f1.y; b[6]=(f16)f1.z; b[7]=(f16)f1.w;
            bf[kk] = b;
        }
        const float* wi = Wih + (size_t)Grow*DD;
        #pragma unroll
        for (int kk = 0; kk < 4; ++kk) {
            const float* p = wi + kk*32 + quad*8;
            float4 f0 = *(const float4*)p, f1 = *(const float4*)(p+4);
            f16x8 b;
            b[0]=(f16)f0.x; b[1]=(f16)f0.y; b[2]=(f16)f0.z; b[3]=(f16)f0.w;
            b[4]=(f16)f1.x; b[5]=(f16)f1.y; b[6]=(f16)f1.z; b[7]=(f16)f1.w;
            bf[8+kk] = b;
        }
    }
    if (tid < 64) {
        const int drow = tid >> 2, ty = tid & 3;
        const int Grow = ty*HH + j0 + drow;
        biasS[tid] = bih[Grow] + bhh[Grow];
    }

    float c = 0.0f;                                  // cell state, resident
    const int pr = tid >> 4;                         // local batch row 0..31
    const int pd = tid & 15;                         // local h-dim 0..15
    const bool ownChunk = ((lane>>2) == hsI);        // own dims come via LDS
    const int dbase = lane*4;                        // dims this lane stages

    for (int t = 0; t < TT; ++t) {
        // ---- stage x_t: 32 rows x 16 16B-chunks (cached loads; pre-poll) ----
        {
            int row = tid >> 4, ch = tid & 15;
            uint4 val = *(const uint4*)(xbuf + ((size_t)(r0+row)*TT + t)*DD + ch*8);
            *(uint4*)(Ast + (size_t)row*392 + 256 + ch*8) = val;
        }
        // ---- stage h_{t-1}: poll 16 tagged words (4 rows x 4 dims) ----
        if (t > 0) {
            if (!ownChunk) {
                const unsigned int* src = hpp + (size_t)((t-1)&1)*BB*HH + dbase;
                const unsigned int tgt = (unsigned)(t-1);
                unsigned int v[4][4];
                bool ok;
                do {
                    ok = true;
                    #pragma unroll
                    for (int rp = 0; rp < 4; ++rp) {
                        const unsigned int* p = src + (size_t)(r0 + wv + rp*8)*HH;
                        #pragma unroll
                        for (int i = 0; i < 4; ++i)
                            v[rp][i] = __hip_atomic_load(p + i, __ATOMIC_RELAXED,
                                                         __HIP_MEMORY_SCOPE_AGENT);
                    }
                    #pragma unroll
                    for (int rp = 0; rp < 4; ++rp)
                        #pragma unroll
                        for (int i = 0; i < 4; ++i)
                            ok &= ((v[rp][i] >> 16) == tgt);
                } while (!ok);
                #pragma unroll
                for (int rp = 0; rp < 4; ++rp) {
                    unsigned int lo = (v[rp][0] & 0xffffu) | (v[rp][1] << 16);
                    unsigned int hi = (v[rp][2] & 0xffffu) | (v[rp][3] << 16);
                    unsigned int* dst = (unsigned int*)
                        (Ast + (size_t)(wv + rp*8)*392 + dbase);
                    dst[0] = lo; dst[1] = hi;
                }
            }
            // own chunks already in Ast (written by elementwise at t-1)
        } else {
            #pragma unroll
            for (int rp = 0; rp < 4; ++rp)
                *(unsigned long long*)(Ast + (size_t)(wv + rp*8)*392 + dbase) = 0ull;
        }
        __syncthreads();   // syncA: Ast complete

        // ---- gates[r][q] = sum_k A[r,k] * W[q,k] ----
        f32x4 acc = {0.f, 0.f, 0.f, 0.f};
        const f16* arow = Ast + (mt*16 + q16)*392 + quad*8;
        #pragma unroll
        for (int kk = 0; kk < 12; ++kk) {
            f16x8 a = *(const f16x8*)(arow + kk*32);
            acc = __builtin_amdgcn_mfma_f32_16x16x32_f16(a, bf[kk], acc, 0, 0, 0);
        }
        // D layout: col=lane&15 -> q, row=quad*4+reg -> m. Store to gbuf[m][q].
        #pragma unroll
        for (int r = 0; r < 4; ++r)
            gbuf[(mt*16 + quad*4 + r)*68 + nt*16 + q16] = acc[r];
        __syncthreads();   // syncB: gates ready (all Ast reads of step t done)

        // ---- elementwise LSTM cell for this thread's (row, dim) ----
        float h;
        {
            const float4 g = *(const float4*)(gbuf + pr*68 + pd*4);
            float gi = g.x + biasS[pd*4+0];
            float gf = g.y + biasS[pd*4+1];
            float gg = g.z + biasS[pd*4+2];
            float go = g.w + biasS[pd*4+3];
            float iv = sigf(gi), fv = sigf(gf), gv = tanhfast(gg), ov = sigf(go);
            c = fv*c + iv*gv;
            h = ov * tanhfast(c);
        }
        // own-slice h -> directly into Ast for step t+1 (no MALL round-trip)
        Ast[pr*392 + j0 + pd] = (f16)h;
        // publish tagged word: validity travels with the data (no drain/flag)
        {
            union { unsigned short us; f16 hf; } cv; cv.hf = (f16)h;
            unsigned int w = ((unsigned)t << 16) | cv.us;
            __hip_atomic_store(hpp + (size_t)(t&1)*BB*HH + (size_t)(r0+pr)*HH + j0 + pd,
                               w, __ATOMIC_RELAXED, __HIP_MEMORY_SCOPE_AGENT);
        }
        // hs for the dense layer: plain cached store, off the critical path
        hs[((size_t)(r0+pr)*TT + t)*HH + j0 + pd] = (f16)h;
        // no syncC: next step's Ast writes touch regions whose readers finished
        // before syncB; publishes are per-word self-validating.
    }
}

// ---------------- K3: dense GEMM, split-K -> partials ----------------
__global__ __launch_bounds__(256) void k_dense(
    const f16* __restrict__ hs, const f16* __restrict__ W3h, float* __restrict__ part)
{
    __shared__ f16 Ap[128*40];
    __shared__ f16 Bp[128*40];
    const int tid = threadIdx.x;
    const int kb = blockIdx.x & 31, tn = (blockIdx.x >> 5) & 1, tm = blockIdx.x >> 6;
    const int m0 = tm*128, n0 = tn*128;
    const long k0 = (long)kb * 2400;
    const int wv = tid >> 6, lane = tid & 63, q16 = lane & 15, quad = lane >> 4;

    f32x4 acc[2][8];
    #pragma unroll
    for (int a = 0; a < 2; ++a)
        #pragma unroll
        for (int b = 0; b < 8; ++b) acc[a][b] = (f32x4){0.f,0.f,0.f,0.f};

    for (int ks = 0; ks < 75; ++ks) {
        const long kbase = k0 + ks*32;
        #pragma unroll
        for (int rep = 0; rep < 4; ++rep) {
            int cid = tid + rep*256;                 // 1024 chunks: 512 A + 512 B
            int selB = cid >> 9;
            int rrow = (cid & 511) >> 2;
            int c4   = cid & 3;
            const f16* src = selB
                ? (W3h + (size_t)(n0+rrow)*KDIM + kbase + c4*8)
                : (hs  + (size_t)(m0+rrow)*KDIM + kbase + c4*8);
            f16* dst = (selB ? Bp : Ap) + rrow*40 + c4*8;
            *(uint4*)dst = *(const uint4*)src;
        }
        __syncthreads();

        f16x8 a0 = *(const f16x8*)(Ap + ((wv*2+0)*16 + q16)*40 + quad*8);
        f16x8 a1 = *(const f16x8*)(Ap + ((wv*2+1)*16 + q16)*40 + quad*8);
        #pragma unroll
        for (int ns = 0; ns < 8; ++ns) {
            f16x8 b = *(const f16x8*)(Bp + (ns*16 + q16)*40 + quad*8);
            acc[0][ns] = __builtin_amdgcn_mfma_f32_16x16x32_f16(a0, b, acc[0][ns], 0,0,0);
            acc[1][ns] = __builtin_amdgcn_mfma_f32_16x16x32_f16(a1, b, acc[1][ns], 0,0,0);
        }
        __syncthreads();
    }
    #pragma unroll
    for (int ms = 0; ms < 2; ++ms)
        #pragma unroll
        for (int ns = 0; ns < 8; ++ns)
            #pragma unroll
            for (int r = 0; r < 4; ++r) {
                int m = m0 + (wv*2+ms)*16 + quad*4 + r;
                int n = n0 + ns*16 + q16;
                part[(size_t)kb*BB*DNS + (size_t)m*DNS + n] = acc[ms][ns][r];
            }
}

// ---------------- K4: reduce split-K partials + bias + relu ----------------
__global__ void k_reduce(const float* __restrict__ part, const float* __restrict__ b3,
                         float* __restrict__ dens)
{
    int g = blockIdx.x * 256 + threadIdx.x;
    if (g >= BB*DNS) return;
    int n = g & 255;
    float s = b3[n];
    #pragma unroll
    for (int kb = 0; kb < 32; ++kb) s += part[(size_t)kb*BB*DNS + g];
    dens[g] = fmaxf(s, 0.0f);
}

// ---------------- K5: final 256->14 + softmax ----------------
__global__ __launch_bounds__(64) void k_final(
    const float* __restrict__ dens, const float* __restrict__ W4,
    const float* __restrict__ b4, float* __restrict__ out)
{
    const int b = blockIdx.x, lane = threadIdx.x;
    const float4 dv = *(const float4*)(dens + (size_t)b*DNS + lane*4);
    float lg[NC];
    #pragma unroll
    for (int cc = 0; cc < NC; ++cc) {
        const float4 w = *(const float4*)(W4 + (size_t)cc*DNS + lane*4);
        float v = dv.x*w.x + dv.y*w.y + dv.z*w.z + dv.w*w.w;
        #pragma unroll
        for (int off = 32; off; off >>= 1) v += __shfl_xor(v, off, 64);
        lg[cc] = v + b4[cc];
    }
    if (lane == 0) {
        float m = lg[0];
        #pragma unroll
        for (int cc = 1; cc < NC; ++cc) m = fmaxf(m, lg[cc]);
        float e[NC], s = 0.f;
        #pragma unroll
        for (int cc = 0; cc < NC; ++cc) { e[cc] = __expf(lg[cc]-m); s += e[cc]; }
        const float inv = 1.0f/s;
        #pragma unroll
        for (int cc = 0; cc < NC; ++cc) out[(size_t)b*NC + cc] = e[cc]*inv;
    }
}

// ---------------- launch ----------------
extern "C" void kernel_launch(void* const* d_in, const int* in_sizes, int n_in,
                              void* d_out, int out_size, void* d_ws, size_t ws_size,
                              hipStream_t stream)
{
    const int*   idx = (const int*)  d_in[0];
    // d_in[1] = traj_lens: unused by the reference
    const float* emb = (const float*)d_in[2];
    const float* Wih = (const float*)d_in[3];
    const float* Whh = (const float*)d_in[4];
    const float* bih = (const float*)d_in[5];
    const float* bhh = (const float*)d_in[6];
    const float* W3  = (const float*)d_in[7];
    const float* b3  = (const float*)d_in[8];
    const float* W4  = (const float*)d_in[9];
    const float* b4  = (const float*)d_in[10];
    float* out = (float*)d_out;

    char* ws = (char*)d_ws;
    f16*   xbuf = (f16*)  (ws);                           // 39,321,600 B
    f16*   hs   = (f16*)  (ws + 39321600);                // 78,643,200 B
    f16*   W3h  = (f16*)  (ws + 117964800);               // 39,321,600 B
    float* part = (float*)(ws + 157286400);               // 16,777,216 B
    float* dens = (float*)(ws + 174063616);               //    524,288 B
    // hpp (tagged h ping-pong, 2x512x256 uint32 = 1 MB) aliases `part`:
    // used only during k_lstm; part written only afterwards by k_dense.
    // Tags self-validate against 0xAA poison -> no memset needed.
    unsigned int* hpp = (unsigned int*)part;

    k_gather<<<19200, 256, 0, stream>>>(idx, emb, xbuf);
    k_w3cvt <<<19200, 256, 0, stream>>>(W3, W3h);
    k_lstm  <<<256, 512, 0, stream>>>(xbuf, hs, Wih, Whh, bih, bhh, hpp);
    k_dense <<<256, 256, 0, stream>>>(hs, W3h, part);
    k_reduce<<<512, 256, 0, stream>>>(part, b3, dens);
    k_final <<<BB, 64, 0, stream>>>(dens, W4, b4, out);
}

// Round 7
// 948.449 us; speedup vs baseline: 1.2665x; 1.2665x over previous
//
#include <hip/hip_runtime.h>

// Problem constants
#define BB    512
#define TT    300
#define DD    128
#define HH    256
#define GG    1024      // 4*H
#define DNS   256
#define NC    14
#define KDIM  76800     // T*H

typedef _Float16 f16;
typedef _Float16 f16x8 __attribute__((ext_vector_type(8)));
typedef float    f32x4 __attribute__((ext_vector_type(4)));

__device__ __forceinline__ float sigf(float x){ return 1.0f / (1.0f + __expf(-x)); }
__device__ __forceinline__ float tanhfast(float x){ return 2.0f / (1.0f + __expf(-2.0f*x)) - 1.0f; }

// ---------------- K1: embedding gather, fp32 -> fp16 x[B][T][D] ----------------
__global__ void k_gather(const int* __restrict__ idx, const float* __restrict__ emb,
                         f16* __restrict__ xbuf)
{
    int gid = blockIdx.x * 256 + threadIdx.x;       // one 4-dim chunk
    if (gid >= BB*TT*DD/4) return;
    int bt = gid >> 5;                              // 32 chunks per 128-dim row
    int c4 = gid & 31;
    int v  = idx[bt];
    const float4 e = *(const float4*)(emb + (size_t)v*DD + c4*4);
    union { f16 h[4]; uint2 u; } o;
    o.h[0]=(f16)e.x; o.h[1]=(f16)e.y; o.h[2]=(f16)e.z; o.h[3]=(f16)e.w;
    *(uint2*)(xbuf + (size_t)bt*DD + c4*4) = o.u;
}

// ---------------- K2: persistent LSTM recurrence ----------------
// Round-7: groups of 4. 256 blocks = 64 batch-slices (8 rows) x 4 slots (64 dims).
// Block owns 256 gate rows; W slice = 96 VGPR/lane, register-resident.
// Exchange: tag-in-word ((t<<16)|f16) in depth-2 ping-pong hpp[t&1][b][dim],
// agent-scope relaxed atomics. Each wave polls ONE row (its wv), each lane 3
// words, with s_sleep(1) backoff (R6's tight spin congested the fabric).
// Wait set per block: 3 producers (was 15); poll lines 96 (was 480).
// Group members {g, g+64, g+128, g+192} -> same XCD under round-robin dispatch
// (perf heuristic only). Depth-2 ping-pong race-free: producer reaches t+2 only
// after consuming h(t+1), which peers publish only after consuming h(t).
__global__ __launch_bounds__(512) void k_lstm(
    const f16* __restrict__ xbuf, f16* __restrict__ hs,
    const float* __restrict__ Wih, const float* __restrict__ Whh,
    const float* __restrict__ bih, const float* __restrict__ bhh,
    unsigned int* hpp)
{
    __shared__ f16   Ast[16*392];    // 16 rows (8 real) x (256 h | 128 x | 8 pad)
    __shared__ float gbuf[16*260];   // gates [m][q], q = 4*d+ty, pad 260
    __shared__ float biasS[256];

    const int tid  = threadIdx.x;
    const int bsI  = blockIdx.x & 63;               // batch-slice (group id)
    const int sI   = blockIdx.x >> 6;               // slot 0..3 (same-XCD swizzle)
    const int r0   = bsI*8, j0 = sI*64;
    const int wv   = tid >> 6, lane = tid & 63;
    const int q16  = lane & 15, quad = lane >> 4;

    // ---- resident W fragments: wave wv owns n-tiles {2wv, 2wv+1} ----
    f16x8 bf[2][12];
    #pragma unroll
    for (int nt = 0; nt < 2; ++nt) {
        const int ql   = (wv*2 + nt)*16 + q16;      // local gate 0..255
        const int drow = ql >> 2, ty = ql & 3;      // q = 4*d + ty
        const int Grow = ty*HH + j0 + drow;         // global gate row
        const float* wh = Whh + (size_t)Grow*HH;
        #pragma unroll
        for (int kk = 0; kk < 8; ++kk) {
            const float* p = wh + kk*32 + quad*8;
            float4 f0 = *(const float4*)p, f1 = *(const float4*)(p+4);
            f16x8 b;
            b[0]=(f16)f0.x; b[1]=(f16)f0.y; b[2]=(f16)f0.z; b[3]=(f16)f0.w;
            b[4]=(f16)f1.x; b[5]=(f16)f1.y; b[6]=(f16)f1.z; b[7]=(f16)f1.w;
            bf[nt][kk] = b;
        }
        const float* wi = Wih + (size_t)Grow*DD;
        #pragma unroll
        for (int kk = 0; kk < 4; ++kk) {
            const float* p = wi + kk*32 + quad*8;
            float4 f0 = *(const float4*)p, f1 = *(const float4*)(p+4);
            f16x8 b;
            b[0]=(f16)f0.x; b[1]=(f16)f0.y; b[2]=(f16)f0.z; b[3]=(f16)f0.w;
            b[4]=(f16)f1.x; b[5]=(f16)f1.y; b[6]=(f16)f1.z; b[7]=(f16)f1.w;
            bf[nt][8+kk] = b;
        }
    }
    if (tid < 256) {
        const int drow = tid >> 2, ty = tid & 3;
        const int Grow = ty*HH + j0 + drow;
        biasS[tid] = bih[Grow] + bhh[Grow];
    }

    float c = 0.0f;                                  // cell state: (row wv, dim lane)
    // this lane's 3 foreign words of row wv: fd = lane*3 + i (192 = 64 lanes x 3)
    const int f0 = lane*3;
    const int d0 = (f0   < j0) ? f0   : f0+64;
    const int d1 = (f0+1 < j0) ? f0+1 : f0+1+64;
    const int d2 = (f0+2 < j0) ? f0+2 : f0+2+64;

    for (int t = 0; t < TT; ++t) {
        // ---- stage x_t: 8 rows x 16 16B-chunks (cached loads; pre-poll) ----
        if (tid < 128) {
            int row = tid >> 4, ch = tid & 15;
            uint4 val = *(const uint4*)(xbuf + ((size_t)(r0+row)*TT + t)*DD + ch*8);
            *(uint4*)(Ast + (size_t)row*392 + 256 + ch*8) = val;
        }
        // ---- stage h_{t-1} foreign dims: poll 3 tagged words with backoff ----
        if (t > 0) {
            unsigned int* pb = hpp + (size_t)((t-1)&1)*BB*HH + (size_t)(r0+wv)*HH;
            const unsigned int tgt = (unsigned)(t-1);
            unsigned int v0, v1, v2;
            for (;;) {
                v0 = __hip_atomic_load(pb+d0, __ATOMIC_RELAXED, __HIP_MEMORY_SCOPE_AGENT);
                v1 = __hip_atomic_load(pb+d1, __ATOMIC_RELAXED, __HIP_MEMORY_SCOPE_AGENT);
                v2 = __hip_atomic_load(pb+d2, __ATOMIC_RELAXED, __HIP_MEMORY_SCOPE_AGENT);
                if (((v0>>16)==tgt) & ((v1>>16)==tgt) & ((v2>>16)==tgt)) break;
                __builtin_amdgcn_s_sleep(1);
            }
            union { unsigned short us; f16 hf; } u0, u1, u2;
            u0.us = (unsigned short)v0; u1.us = (unsigned short)v1; u2.us = (unsigned short)v2;
            Ast[wv*392 + d0] = u0.hf;
            Ast[wv*392 + d1] = u1.hf;
            Ast[wv*392 + d2] = u2.hf;
            // own 64 dims already in Ast (written by elementwise at t-1)
        } else {
            Ast[wv*392 + d0] = (f16)0.f;
            Ast[wv*392 + d1] = (f16)0.f;
            Ast[wv*392 + d2] = (f16)0.f;
            Ast[wv*392 + j0 + lane] = (f16)0.f;      // own dims
        }
        __syncthreads();   // syncA: Ast complete (rows 8..15 garbage: C rows unused)

        // ---- gates[m][q] = sum_k A[m,k] * W[q,k]; wave = 2 n-tiles, M=16 ----
        f32x4 acc0 = {0.f,0.f,0.f,0.f}, acc1 = {0.f,0.f,0.f,0.f};
        const f16* arow = Ast + q16*392 + quad*8;
        #pragma unroll
        for (int kk = 0; kk < 12; ++kk) {
            f16x8 a = *(const f16x8*)(arow + kk*32);
            acc0 = __builtin_amdgcn_mfma_f32_16x16x32_f16(a, bf[0][kk], acc0, 0, 0, 0);
            acc1 = __builtin_amdgcn_mfma_f32_16x16x32_f16(a, bf[1][kk], acc1, 0, 0, 0);
        }
        // D layout: col=lane&15 -> q within tile, row=quad*4+r -> m
        #pragma unroll
        for (int r = 0; r < 4; ++r) {
            gbuf[(quad*4+r)*260 + (wv*2+0)*16 + q16] = acc0[r];
            gbuf[(quad*4+r)*260 + (wv*2+1)*16 + q16] = acc1[r];
        }
        __syncthreads();   // syncB: gates ready (all Ast reads of step t done)

        // ---- elementwise LSTM cell: (row wv, dim lane) ----
        float h;
        {
            const float4 g = *(const float4*)(gbuf + wv*260 + lane*4);
            const float4 bs = *(const float4*)(biasS + lane*4);
            float gi = g.x + bs.x;
            float gf = g.y + bs.y;
            float gg = g.z + bs.z;
            float go = g.w + bs.w;
            float iv = sigf(gi), fv = sigf(gf), gv = tanhfast(gg), ov = sigf(go);
            c = fv*c + iv*gv;
            h = ov * tanhfast(c);
        }
        union { unsigned short us; f16 hf; } cv; cv.hf = (f16)h;
        // publish first (tagged word: validity travels with data, per-lane dword)
        __hip_atomic_store(hpp + (size_t)(t&1)*BB*HH + (size_t)(r0+wv)*HH + j0 + lane,
                           ((unsigned)t << 16) | cv.us,
                           __ATOMIC_RELAXED, __HIP_MEMORY_SCOPE_AGENT);
        // own slice -> Ast for step t+1 (no fabric round-trip)
        Ast[wv*392 + j0 + lane] = cv.hf;
        // hs for the dense layer: plain cached store, off the critical path
        hs[((size_t)(r0+wv)*TT + t)*HH + j0 + lane] = cv.hf;
        // no third barrier: next step's Ast writes hit regions whose readers
        // finished before syncB; publishes are per-word self-validating.
    }
}

// ---------------- K3: dense GEMM, split-K -> partials ----------------
// A = hs (fp16), B = W3 (fp32, converted to fp16 during LDS staging -> no
// separate 236MB convert pass). dens[m][n] = sum_k hs[m,k]*W3[n,k].
__global__ __launch_bounds__(256) void k_dense(
    const f16* __restrict__ hs, const float* __restrict__ W3, float* __restrict__ part)
{
    __shared__ f16 Ap[128*40];
    __shared__ f16 Bp[128*40];
    const int tid = threadIdx.x;
    const int kb = blockIdx.x & 31, tn = (blockIdx.x >> 5) & 1, tm = blockIdx.x >> 6;
    const int m0 = tm*128, n0 = tn*128;
    const long k0 = (long)kb * 2400;
    const int wv = tid >> 6, lane = tid & 63, q16 = lane & 15, quad = lane >> 4;

    f32x4 acc[2][8];
    #pragma unroll
    for (int a = 0; a < 2; ++a)
        #pragma unroll
        for (int b = 0; b < 8; ++b) acc[a][b] = (f32x4){0.f,0.f,0.f,0.f};

    for (int ks = 0; ks < 75; ++ks) {
        const long kbase = k0 + ks*32;
        #pragma unroll
        for (int rep = 0; rep < 4; ++rep) {
            int cid = tid + rep*256;                 // 1024 chunks: 512 A + 512 B
            int rrow = (cid & 511) >> 2;
            int c4   = cid & 3;
            if (cid < 512) {
                const f16* src = hs + (size_t)(m0+rrow)*KDIM + kbase + c4*8;
                *(uint4*)(Ap + rrow*40 + c4*8) = *(const uint4*)src;
            } else {
                const float* src = W3 + (size_t)(n0+rrow)*KDIM + kbase + c4*8;
                float4 f0 = *(const float4*)src, f1 = *(const float4*)(src+4);
                union { f16 h[8]; uint4 u; } o;
                o.h[0]=(f16)f0.x; o.h[1]=(f16)f0.y; o.h[2]=(f16)f0.z; o.h[3]=(f16)f0.w;
                o.h[4]=(f16)f1.x; o.h[5]=(f16)f1.y; o.h[6]=(f16)f1.z; o.h[7]=(f16)f1.w;
                *(uint4*)(Bp + rrow*40 + c4*8) = o.u;
            }
        }
        __syncthreads();

        f16x8 a0 = *(const f16x8*)(Ap + ((wv*2+0)*16 + q16)*40 + quad*8);
        f16x8 a1 = *(const f16x8*)(Ap + ((wv*2+1)*16 + q16)*40 + quad*8);
        #pragma unroll
        for (int ns = 0; ns < 8; ++ns) {
            f16x8 b = *(const f16x8*)(Bp + (ns*16 + q16)*40 + quad*8);
            acc[0][ns] = __builtin_amdgcn_mfma_f32_16x16x32_f16(a0, b, acc[0][ns], 0,0,0);
            acc[1][ns] = __builtin_amdgcn_mfma_f32_16x16x32_f16(a1, b, acc[1][ns], 0,0,0);
        }
        __syncthreads();
    }
    #pragma unroll
    for (int ms = 0; ms < 2; ++ms)
        #pragma unroll
        for (int ns = 0; ns < 8; ++ns)
            #pragma unroll
            for (int r = 0; r < 4; ++r) {
                int m = m0 + (wv*2+ms)*16 + quad*4 + r;
                int n = n0 + ns*16 + q16;
                part[(size_t)kb*BB*DNS + (size_t)m*DNS + n] = acc[ms][ns][r];
            }
}

// ---------------- K4: reduce split-K partials + bias + relu ----------------
__global__ void k_reduce(const float* __restrict__ part, const float* __restrict__ b3,
                         float* __restrict__ dens)
{
    int g = blockIdx.x * 256 + threadIdx.x;
    if (g >= BB*DNS) return;
    int n = g & 255;
    float s = b3[n];
    #pragma unroll
    for (int kb = 0; kb < 32; ++kb) s += part[(size_t)kb*BB*DNS + g];
    dens[g] = fmaxf(s, 0.0f);
}

// ---------------- K5: final 256->14 + softmax ----------------
__global__ __launch_bounds__(64) void k_final(
    const float* __restrict__ dens, const float* __restrict__ W4,
    const float* __restrict__ b4, float* __restrict__ out)
{
    const int b = blockIdx.x, lane = threadIdx.x;
    const float4 dv = *(const float4*)(dens + (size_t)b*DNS + lane*4);
    float lg[NC];
    #pragma unroll
    for (int cc = 0; cc < NC; ++cc) {
        const float4 w = *(const float4*)(W4 + (size_t)cc*DNS + lane*4);
        float v = dv.x*w.x + dv.y*w.y + dv.z*w.z + dv.w*w.w;
        #pragma unroll
        for (int off = 32; off; off >>= 1) v += __shfl_xor(v, off, 64);
        lg[cc] = v + b4[cc];
    }
    if (lane == 0) {
        float m = lg[0];
        #pragma unroll
        for (int cc = 1; cc < NC; ++cc) m = fmaxf(m, lg[cc]);
        float e[NC], s = 0.f;
        #pragma unroll
        for (int cc = 0; cc < NC; ++cc) { e[cc] = __expf(lg[cc]-m); s += e[cc]; }
        const float inv = 1.0f/s;
        #pragma unroll
        for (int cc = 0; cc < NC; ++cc) out[(size_t)b*NC + cc] = e[cc]*inv;
    }
}

// ---------------- launch ----------------
extern "C" void kernel_launch(void* const* d_in, const int* in_sizes, int n_in,
                              void* d_out, int out_size, void* d_ws, size_t ws_size,
                              hipStream_t stream)
{
    const int*   idx = (const int*)  d_in[0];
    // d_in[1] = traj_lens: unused by the reference
    const float* emb = (const float*)d_in[2];
    const float* Wih = (const float*)d_in[3];
    const float* Whh = (const float*)d_in[4];
    const float* bih = (const float*)d_in[5];
    const float* bhh = (const float*)d_in[6];
    const float* W3  = (const float*)d_in[7];
    const float* b3  = (const float*)d_in[8];
    const float* W4  = (const float*)d_in[9];
    const float* b4  = (const float*)d_in[10];
    float* out = (float*)d_out;

    char* ws = (char*)d_ws;
    f16*   xbuf = (f16*)  (ws);                           // 39,321,600 B
    f16*   hs   = (f16*)  (ws + 39321600);                // 78,643,200 B
    float* part = (float*)(ws + 117964800);               // 16,777,216 B
    float* dens = (float*)(ws + 134742016);               //    524,288 B
    // hpp (tagged h ping-pong, 2x512x256 uint32 = 1 MB) aliases `part`:
    // used only during k_lstm; part written only afterwards by k_dense.
    // Tags self-validate against 0xAA poison -> no memset needed.
    unsigned int* hpp = (unsigned int*)part;

    k_gather<<<19200, 256, 0, stream>>>(idx, emb, xbuf);
    k_lstm  <<<256, 512, 0, stream>>>(xbuf, hs, Wih, Whh, bih, bhh, hpp);
    k_dense <<<256, 256, 0, stream>>>(hs, W3, part);
    k_reduce<<<512, 256, 0, stream>>>(part, b3, dens);
    k_final <<<BB, 64, 0, stream>>>(dens, W4, b4, out);
}